// Round 14
// baseline (687.155 us; speedup 1.0000x reference)
//
#include <hip/hip_runtime.h>

#define SEQ 4096
#define HID 512
#define NB  4
#define N3  1536
#define LOG2E 1.4426950408889634f

typedef _Float16 half_t;
typedef __attribute__((ext_vector_type(8))) _Float16 half8;
typedef __attribute__((ext_vector_type(4))) float f32x4;

#define GLOAD_LDS16(gp, lp) __builtin_amdgcn_global_load_lds((gp), (lp), 16, 0, 0)

#define LGKM_BARRIER()                                                       \
  asm volatile("s_waitcnt lgkmcnt(0)" ::: "memory");                         \
  __builtin_amdgcn_sched_barrier(0);                                         \
  __builtin_amdgcn_s_barrier();

// ---------------- convert x (f32) -> f16 ----------------
__global__ void k_cvt(const float* __restrict__ x, half_t* __restrict__ xh, int n4) {
  int i = blockIdx.x * blockDim.x + threadIdx.x;
  int stride = gridDim.x * blockDim.x;
  for (; i < n4; i += stride) {
    float4 v = reinterpret_cast<const float4*>(x)[i];
    union { half_t h[4]; short4 s; } u;
    u.h[0] = (half_t)v.x; u.h[1] = (half_t)v.y;
    u.h[2] = (half_t)v.z; u.h[3] = (half_t)v.w;
    reinterpret_cast<short4*>(xh)[i] = u.s;
  }
}

// ---------------- W [512][1536] f32 -> Wt [1536][512] f16 ----------------
__global__ void k_tw(const float* __restrict__ W, half_t* __restrict__ Wt) {
  __shared__ half_t tile[64][65];
  const int n0 = blockIdx.x * 64;
  const int k0 = blockIdx.y * 64;
  const int tx = threadIdx.x & 63, ty = threadIdx.x >> 6;
#pragma unroll
  for (int i = 0; i < 64; i += 4)
    tile[ty + i][tx] = (half_t)W[(size_t)(k0 + ty + i) * N3 + n0 + tx];
  __syncthreads();
#pragma unroll
  for (int i = 0; i < 64; i += 4)
    Wt[(size_t)(n0 + ty + i) * HID + k0 + tx] = tile[tx][ty + i];
}

// ---------------- QKV projection GEMM (V written fragment-packed) ----------------
__launch_bounds__(256)
__global__ void k_qkv(const half_t* __restrict__ xh, const half_t* __restrict__ Wt,
                      const float* __restrict__ bias,
                      half_t* __restrict__ Qh, half_t* __restrict__ Kh,
                      half_t* __restrict__ Vf) {
  __shared__ half_t sA[128 * 32];
  __shared__ half_t sB[128 * 32];
  const int t = threadIdx.x;
  const int m0 = blockIdx.y * 128;
  const int n0 = blockIdx.x * 128;
  const int lane = t & 63, wid = t >> 6;
  const int wr = (wid >> 1) * 64, wc = (wid & 1) * 64;
  const int lrow = lane & 15, lks = lane >> 4;
  const int s1 = t, s2 = t + 256;
  const int ar1 = s1 >> 2, ac1 = (s1 & 3) * 8;
  const int ar2 = s2 >> 2, ac2 = (s2 & 3) * 8;

  f32x4 acc[4][4] = {};

  for (int k0 = 0; k0 < HID; k0 += 32) {
    __syncthreads();
    GLOAD_LDS16(xh + (size_t)(m0 + ar1) * HID + k0 + ac1, &sA[s1 * 8]);
    GLOAD_LDS16(xh + (size_t)(m0 + ar2) * HID + k0 + ac2, &sA[s2 * 8]);
    GLOAD_LDS16(Wt + (size_t)(n0 + ar1) * HID + k0 + ac1, &sB[s1 * 8]);
    GLOAD_LDS16(Wt + (size_t)(n0 + ar2) * HID + k0 + ac2, &sB[s2 * 8]);
    __syncthreads();
    half8 a[4], b[4];
#pragma unroll
    for (int m = 0; m < 4; ++m)
      a[m] = *reinterpret_cast<const half8*>(&sA[(wr + m * 16 + lrow) * 32 + lks * 8]);
#pragma unroll
    for (int n = 0; n < 4; ++n)
      b[n] = *reinterpret_cast<const half8*>(&sB[(wc + n * 16 + lrow) * 32 + lks * 8]);
#pragma unroll
    for (int m = 0; m < 4; ++m)
#pragma unroll
      for (int n = 0; n < 4; ++n)
        acc[m][n] = __builtin_amdgcn_mfma_f32_16x16x32_f16(a[m], b[n], acc[m][n], 0, 0, 0);
  }

  const float scale = 0.04419417382415922f;  // 1/sqrt(512)
  const int region = n0 >> 9;  // 0=Q, 1=K, 2=V (uniform per block)
#pragma unroll
  for (int m = 0; m < 4; ++m) {
#pragma unroll
    for (int n = 0; n < 4; ++n) {
      const int col = n0 + wc + n * 16 + lrow;
#pragma unroll
      for (int r = 0; r < 4; ++r) {
        const int row = m0 + wr + m * 16 + lks * 4 + r;
        float v = acc[m][n][r] + bias[col];
        if (region == 0) {
          Qh[(size_t)row * HID + col] = (half_t)(v * scale);
        } else if (region == 1) {
          Kh[(size_t)row * HID + (col - 512)] = (half_t)v;
        } else {
          const int bb = row >> 12, s = row & (SEQ - 1), h = col - 1024;
          const int tl = bb * 4096 + (s >> 5) * 32 + (h >> 4);
          Vf[(size_t)tl * 512 + (((h & 15) | (((s >> 3) & 3) << 4)) * 8) + (s & 7)] =
              (half_t)v;
        }
      }
    }
  }
}

// ---------------- scores = Q @ K^T -> f16 raw scores + softmax partials ----------
// FRAG=1: fragment-packed Shf tiles (16 rows x 32 keys, MFMA-A lane order).
// FRAG=0: row-packed into attn rows' upper halves (fallback).
template <int FRAG>
__launch_bounds__(256)
__global__ void k_qk(const half_t* __restrict__ Qh, const half_t* __restrict__ Kh,
                     half_t* __restrict__ Sh, float2* __restrict__ part) {
  __shared__ half_t sA[128 * 32];
  __shared__ half_t sB[128 * 32];
  __shared__ float lm[2][128], ls[2][128];
  const int t = threadIdx.x;
  const int bz = blockIdx.z;
  const half_t* A = Qh + (size_t)bz * SEQ * HID;
  const half_t* B = Kh + (size_t)bz * SEQ * HID;
  const int m0 = blockIdx.y * 128;
  const int n0 = blockIdx.x * 128;
  const int lane = t & 63, wid = t >> 6;
  const int wr = (wid >> 1) * 64, wc = (wid & 1) * 64;
  const int lrow = lane & 15, lks = lane >> 4;
  const int s1 = t, s2 = t + 256;
  const int ar1 = s1 >> 2, ac1 = (s1 & 3) * 8;
  const int ar2 = s2 >> 2, ac2 = (s2 & 3) * 8;

  f32x4 acc[4][4] = {};

  for (int k0 = 0; k0 < HID; k0 += 32) {
    __syncthreads();
    GLOAD_LDS16(A + (size_t)(m0 + ar1) * HID + k0 + ac1, &sA[s1 * 8]);
    GLOAD_LDS16(A + (size_t)(m0 + ar2) * HID + k0 + ac2, &sA[s2 * 8]);
    GLOAD_LDS16(B + (size_t)(n0 + ar1) * HID + k0 + ac1, &sB[s1 * 8]);
    GLOAD_LDS16(B + (size_t)(n0 + ar2) * HID + k0 + ac2, &sB[s2 * 8]);
    __syncthreads();
    half8 a[4], b[4];
#pragma unroll
    for (int m = 0; m < 4; ++m)
      a[m] = *reinterpret_cast<const half8*>(&sA[(wr + m * 16 + lrow) * 32 + lks * 8]);
#pragma unroll
    for (int n = 0; n < 4; ++n)
      b[n] = *reinterpret_cast<const half8*>(&sB[(wc + n * 16 + lrow) * 32 + lks * 8]);
#pragma unroll
    for (int m = 0; m < 4; ++m)
#pragma unroll
      for (int n = 0; n < 4; ++n)
        acc[m][n] = __builtin_amdgcn_mfma_f32_16x16x32_f16(a[m], b[n], acc[m][n], 0, 0, 0);
  }

  // f16 raw-score write
#pragma unroll
  for (int m = 0; m < 4; ++m)
#pragma unroll
    for (int n = 0; n < 4; ++n)
#pragma unroll
      for (int r = 0; r < 4; ++r) {
        const int row = m0 + wr + m * 16 + lks * 4 + r;
        const int key = n0 + wc + n * 16 + lrow;
        if (FRAG) {
          Sh[((size_t)(bz * 128 + (key >> 5)) * 256 + (row >> 4)) * 512 +
             (((row & 15) | (((key >> 3) & 3) << 4)) * 8) + (key & 7)] =
              (half_t)acc[m][n][r];
        } else {
          Sh[((size_t)bz * SEQ + row) * (2 * SEQ) + SEQ + key] = (half_t)acc[m][n][r];
        }
      }

  // per-tile softmax partials
#pragma unroll
  for (int m = 0; m < 4; ++m) {
#pragma unroll
    for (int r = 0; r < 4; ++r) {
      float mx = fmaxf(fmaxf(acc[m][0][r], acc[m][1][r]),
                       fmaxf(acc[m][2][r], acc[m][3][r]));
      mx = fmaxf(mx, __shfl_xor(mx, 1));
      mx = fmaxf(mx, __shfl_xor(mx, 2));
      mx = fmaxf(mx, __shfl_xor(mx, 4));
      mx = fmaxf(mx, __shfl_xor(mx, 8));
      float s = expf(acc[m][0][r] - mx) + expf(acc[m][1][r] - mx) +
                expf(acc[m][2][r] - mx) + expf(acc[m][3][r] - mx);
      s += __shfl_xor(s, 1);
      s += __shfl_xor(s, 2);
      s += __shfl_xor(s, 4);
      s += __shfl_xor(s, 8);
      if (lrow == 0) {
        const int rr = wr + m * 16 + lks * 4 + r;
        lm[wid & 1][rr] = mx;
        ls[wid & 1][rr] = s;
      }
    }
  }
  __syncthreads();
  if (t < 128) {
    const float m0v = lm[0][t], m1v = lm[1][t];
    const float M = fmaxf(m0v, m1v);
    const float L = ls[0][t] * expf(m0v - M) + ls[1][t] * expf(m1v - M);
    part[(size_t)(bz * SEQ + m0 + t) * 32 + blockIdx.x] = make_float2(M, L);
  }
}

// ---------------- merge 32 per-tile partials per row -> (rowmax, 1/rowsum) --------
__global__ void k_lred(const float2* __restrict__ part, float2* __restrict__ stats) {
  const int row = blockIdx.x * 256 + threadIdx.x;  // [0, NB*SEQ)
  const float2* p = part + (size_t)row * 32;
  float M = -3.4028235e38f;
#pragma unroll
  for (int i = 0; i < 32; ++i) M = fmaxf(M, p[i].x);
  float L = 0.f;
#pragma unroll
  for (int i = 0; i < 32; ++i) L += p[i].y * expf(p[i].x - M);
  stats[row] = make_float2(M, 1.0f / L);
}

// ---------------- BARRIER-FREE fused PV, row-partitioned waves ----------------
// 512 blocks x 4 waves; wave = 16 PRIVATE rows x 256 cols (acc 64 VGPR).
// A-frags (Shf tiles) are per-wave-private -> exp computed once per col-half
// (2x total, was 8x in R13). il folded into exponent: e = exp2(s*log2e - m2p),
// f32 e IS the attn value. A 2-deep register prefetch; V frags L2-resident.
// No LDS, no barriers.
__launch_bounds__(256, 3)
__global__ void k_pvg(const half_t* __restrict__ Shf, const half_t* __restrict__ Vf,
                      const float2* __restrict__ stats,
                      float* __restrict__ attn, float* __restrict__ O) {
  const int t = threadIdx.x;
  const int bid = blockIdx.x;
  const int sw = (bid & 7) * 64 + (bid >> 3);  // bijective XCD swizzle (512)
  const int rb = sw >> 1;                      // row-block 0..255
  const int ch = sw & 1;                       // col half
  const int bz = rb >> 6;
  const int m0 = (rb & 63) * 64;
  const int c0 = ch * 256;
  const int lane = t & 63, w = t >> 6;
  const int lrow = lane & 15, lks = lane >> 4;

  const int rg = (m0 >> 4) + w;                // this wave's row-group in batch
  const int rowA = m0 + w * 16 + lrow;         // this lane's exp/A row
  const float2 st = stats[(size_t)bz * SEQ + rowA];
  const float m2p = st.x * LOG2E - __log2f(st.y);

  const half_t* const abase =
      Shf + ((size_t)(bz * 128) * 256 + rg) * 512 + lane * 8;
  const half_t* const vb =
      Vf + ((size_t)bz * 4096 + (c0 >> 4)) * 512 + lane * 8;
  float* const arow =
      attn + (size_t)bz * SEQ * SEQ + (size_t)rowA * SEQ + lks * 8;
  float* const Ob = O + (size_t)bz * SEQ * HID;

  f32x4 acc[16] = {};
  half8 arA, arB;
  arA = *reinterpret_cast<const half8*>(abase);
  arB = *reinterpret_cast<const half8*>(abase + (size_t)256 * 512);

#define PVG_STEP(AR, KC)                                                     \
  {                                                                          \
    f32x4 e0, e1;                                                            \
    half8 ah;                                                                \
    _Pragma("unroll")                                                        \
    for (int j = 0; j < 4; ++j) {                                            \
      e0[j] = exp2f((float)(AR)[j] * LOG2E - m2p);                           \
      e1[j] = exp2f((float)(AR)[j + 4] * LOG2E - m2p);                       \
    }                                                                        \
    _Pragma("unroll")                                                        \
    for (int j = 0; j < 4; ++j) {                                            \
      ah[j] = (half_t)e0[j];                                                 \
      ah[j + 4] = (half_t)e1[j];                                             \
    }                                                                        \
    if ((KC) + 2 < 128)                                                      \
      AR = *reinterpret_cast<const half8*>(abase +                           \
                                           (size_t)((KC) + 2) * 256 * 512);  \
    *reinterpret_cast<f32x4*>(arow + (KC) * 32) = e0;                        \
    *reinterpret_cast<f32x4*>(arow + (KC) * 32 + 4) = e1;                    \
    _Pragma("unroll")                                                        \
    for (int g = 0; g < 2; ++g) {                                            \
      half8 bv[8];                                                           \
      _Pragma("unroll")                                                      \
      for (int n = 0; n < 8; ++n)                                            \
        bv[n] = *reinterpret_cast<const half8*>(                             \
            vb + ((size_t)(KC) * 32 + g * 8 + n) * 512);                     \
      _Pragma("unroll")                                                      \
      for (int n = 0; n < 8; ++n)                                            \
        acc[g * 8 + n] = __builtin_amdgcn_mfma_f32_16x16x32_f16(             \
            ah, bv[n], acc[g * 8 + n], 0, 0, 0);                             \
    }                                                                        \
  }

  for (int kc = 0; kc < 128; kc += 2) {
    PVG_STEP(arA, kc);
    PVG_STEP(arB, kc + 1);
  }

#pragma unroll
  for (int n = 0; n < 16; ++n)
#pragma unroll
    for (int r = 0; r < 4; ++r)
      Ob[(size_t)(m0 + w * 16 + lks * 4 + r) * HID + c0 + n * 16 + lrow] =
          acc[n][r];
}

// ---------------- fallback PV (R9 known-good) ----------------
__launch_bounds__(512, 4)
__global__ void k_pvn(float* __restrict__ P, const half_t* __restrict__ Vf,
                      const float2* __restrict__ stats, float* __restrict__ O) {
  __shared__ half_t sA[4][32 * 64];
  const int t = threadIdx.x;
  const int bid = blockIdx.x;
  const int sw = (bid & 7) * 64 + (bid >> 3);
  const int bz = sw >> 7;
  const int m0 = (sw & 127) * 32;

  float* Pb = P + (size_t)bz * SEQ * SEQ;
  float* Ob = O + (size_t)bz * SEQ * HID;

  const int lane = t & 63, wid = t >> 6;
  const int lrow = lane & 15, lks = lane >> 4;

  const int prow = t >> 4;
  const int pc = t & 15;
  const float2 st = stats[(size_t)bz * SEQ + m0 + prow];
  const float mrow2 = st.x * LOG2E, invl = st.y;

  float* const PArow = Pb + (size_t)(m0 + prow) * SEQ + pc * 8;
  const half_t* const Shrow =
      (const half_t*)(Pb + (size_t)(m0 + prow) * SEQ) + SEQ + pc * 8;

  const int schunk = pc >> 3;
  const int sidx = prow * 64 + (((pc & 7) ^ (prow & 7)) << 3);

  int aoff[2][2];
#pragma unroll
  for (int m = 0; m < 2; ++m)
#pragma unroll
    for (int kk = 0; kk < 2; ++kk) {
      const int row = m * 16 + lrow;
      aoff[m][kk] = row * 64 + (((kk * 4 + lks) ^ (row & 7)) << 3);
    }

  const half_t* const vb =
      Vf + (size_t)bz * 4096 * 512 + (size_t)(wid * 4) * 512 + lane * 8;

  f32x4 acc[2][4] = {};
  f32x4 e0, e1;
  half8 prA, prB;

#define PV_EXPSTAGE(SB, PR)                                                  \
  {                                                                          \
    _Pragma("unroll")                                                        \
    for (int j = 0; j < 4; ++j) {                                            \
      e0[j] = exp2f((float)(PR)[j] * LOG2E - mrow2) * invl;                  \
      e1[j] = exp2f((float)(PR)[j + 4] * LOG2E - mrow2) * invl;              \
    }                                                                        \
    half8 hv;                                                                \
    _Pragma("unroll")                                                        \
    for (int j = 0; j < 4; ++j) {                                            \
      hv[j] = (half_t)e0[j];                                                 \
      hv[j + 4] = (half_t)e1[j];                                             \
    }                                                                        \
    *reinterpret_cast<half8*>(&sA[(SB) * 2 + schunk][sidx]) = hv;            \
  }

#define PV_ITER(PRL, PRC, SC)                                                \
  {                                                                          \
    half8 b[16];                                                             \
    _Pragma("unroll")                                                        \
    for (int kc = 0; kc < 4; ++kc)                                           \
      _Pragma("unroll")                                                      \
      for (int n = 0; n < 4; ++n)                                            \
        b[kc * 4 + n] = *reinterpret_cast<const half8*>(                     \
            vb + ((size_t)((SC) * 4 + kc) * 32 + n) * 512);                  \
    if ((SC) + 2 < 32)                                                       \
      PRL = *reinterpret_cast<const half8*>(Shrow + ((SC) + 2) * 128);       \
    *reinterpret_cast<f32x4*>(PArow + (SC) * 128) = e0;                      \
    *reinterpret_cast<f32x4*>(PArow + (SC) * 128 + 4) = e1;                  \
    __builtin_amdgcn_sched_barrier(0);                                       \
    _Pragma("unroll")                                                        \
    for (int kc = 0; kc < 4; ++kc) {                                         \
      const int cb = ((SC) & 1) * 2 + (kc >> 1);                             \
      half8 a[2];                                                            \
      _Pragma("unroll")                                                      \
      for (int m = 0; m < 2; ++m)                                            \
        a[m] = *reinterpret_cast<const half8*>(&sA[cb][aoff[m][kc & 1]]);    \
      _Pragma("unroll")                                                      \
      for (int m = 0; m < 2; ++m)                                            \
        _Pragma("unroll")                                                    \
        for (int n = 0; n < 4; ++n)                                          \
          acc[m][n] = __builtin_amdgcn_mfma_f32_16x16x32_f16(                \
              a[m], b[kc * 4 + n], acc[m][n], 0, 0, 0);                      \
    }                                                                        \
    if ((SC) + 1 < 32) {                                                     \
      PV_EXPSTAGE(((SC) + 1) & 1, PRC);                                      \
    }                                                                        \
    LGKM_BARRIER();                                                          \
  }

  {
    half8 pr0 = *reinterpret_cast<const half8*>(Shrow);
    PV_EXPSTAGE(0, pr0);
    prB = *reinterpret_cast<const half8*>(Shrow + 128);
    LGKM_BARRIER();
  }

  for (int sc = 0; sc < 32; sc += 2) {
    PV_ITER(prA, prB, sc);
    PV_ITER(prB, prA, sc + 1);
  }

#pragma unroll
  for (int m = 0; m < 2; ++m)
#pragma unroll
    for (int n = 0; n < 4; ++n)
#pragma unroll
      for (int r = 0; r < 4; ++r)
        Ob[(size_t)(m0 + m * 16 + lks * 4 + r) * HID + (wid * 64 + n * 16 + lrow)] =
            acc[m][n][r];
}

extern "C" void kernel_launch(void* const* d_in, const int* in_sizes, int n_in,
                              void* d_out, int out_size, void* d_ws, size_t ws_size,
                              hipStream_t stream) {
  const float* x = (const float*)d_in[0];     // [4,4096,512]
  const float* W = (const float*)d_in[1];     // [512,1536]
  const float* bias = (const float*)d_in[2];  // [1536]
  float* opt = (float*)d_out;                        // [4*4096*512]
  float* attn = opt + (size_t)NB * SEQ * HID;        // [4*4096*4096]

  half_t* xh = (half_t*)d_ws;                        // 16.78 MB
  half_t* Wt = xh + (size_t)NB * SEQ * HID;          // 1.57 MB
  half_t* Qh = Wt + (size_t)N3 * HID;                // 16.78 MB
  half_t* Kh = Qh + (size_t)NB * SEQ * HID;          // 16.78 MB
  half_t* Vf = Kh + (size_t)NB * SEQ * HID;          // 16.78 MB (fragment-packed)
  float2* part = (float2*)(Vf + (size_t)NB * HID * SEQ);  // 4.19 MB
  float2* stats = part + (size_t)NB * SEQ * 32;           // 131 KB
  half_t* Shf = (half_t*)(stats + NB * SEQ);              // 134.2 MB (frag scores)
  const size_t need = (size_t)((char*)(Shf + (size_t)NB * SEQ * SEQ) - (char*)d_ws);
  const bool frag = ws_size >= need;

  k_cvt<<<2048, 256, 0, stream>>>(x, xh, NB * SEQ * HID / 4);
  k_tw<<<dim3(N3 / 64, HID / 64), 256, 0, stream>>>(W, Wt);
  k_qkv<<<dim3(N3 / 128, NB * SEQ / 128), 256, 0, stream>>>(xh, Wt, bias, Qh, Kh, Vf);
  if (frag) {
    k_qk<1><<<dim3(SEQ / 128, SEQ / 128, NB), 256, 0, stream>>>(Qh, Kh, Shf, part);
    k_lred<<<NB * SEQ / 256, 256, 0, stream>>>(part, stats);
    k_pvg<<<512, 256, 0, stream>>>(Shf, Vf, stats, attn, opt);
  } else {
    k_qk<0><<<dim3(SEQ / 128, SEQ / 128, NB), 256, 0, stream>>>(Qh, Kh, (half_t*)attn,
                                                                part);
    k_lred<<<NB * SEQ / 256, 256, 0, stream>>>(part, stats);
    k_pvn<<<512, 512, 0, stream>>>(attn, Vf, stats, opt);
  }
}

// Round 15
// 603.376 us; speedup vs baseline: 1.1389x; 1.1389x over previous
//
#include <hip/hip_runtime.h>

#define SEQ 4096
#define HID 512
#define NB  4
#define N3  1536
#define LOG2E 1.4426950408889634f

typedef _Float16 half_t;
typedef __attribute__((ext_vector_type(8))) _Float16 half8;
typedef __attribute__((ext_vector_type(4))) float f32x4;

#define GLOAD_LDS16(gp, lp) __builtin_amdgcn_global_load_lds((gp), (lp), 16, 0, 0)

#define LGKM_BARRIER()                                                       \
  asm volatile("s_waitcnt lgkmcnt(0)" ::: "memory");                         \
  __builtin_amdgcn_sched_barrier(0);                                         \
  __builtin_amdgcn_s_barrier();

// ---------------- convert x (f32) -> f16 ----------------
__global__ void k_cvt(const float* __restrict__ x, half_t* __restrict__ xh, int n4) {
  int i = blockIdx.x * blockDim.x + threadIdx.x;
  int stride = gridDim.x * blockDim.x;
  for (; i < n4; i += stride) {
    float4 v = reinterpret_cast<const float4*>(x)[i];
    union { half_t h[4]; short4 s; } u;
    u.h[0] = (half_t)v.x; u.h[1] = (half_t)v.y;
    u.h[2] = (half_t)v.z; u.h[3] = (half_t)v.w;
    reinterpret_cast<short4*>(xh)[i] = u.s;
  }
}

// ---------------- W [512][1536] f32 -> Wt [1536][512] f16 ----------------
__global__ void k_tw(const float* __restrict__ W, half_t* __restrict__ Wt) {
  __shared__ half_t tile[64][65];
  const int n0 = blockIdx.x * 64;
  const int k0 = blockIdx.y * 64;
  const int tx = threadIdx.x & 63, ty = threadIdx.x >> 6;
#pragma unroll
  for (int i = 0; i < 64; i += 4)
    tile[ty + i][tx] = (half_t)W[(size_t)(k0 + ty + i) * N3 + n0 + tx];
  __syncthreads();
#pragma unroll
  for (int i = 0; i < 64; i += 4)
    Wt[(size_t)(n0 + ty + i) * HID + k0 + tx] = tile[tx][ty + i];
}

// ---------------- QKV projection GEMM (V written fragment-packed) ----------------
__launch_bounds__(256)
__global__ void k_qkv(const half_t* __restrict__ xh, const half_t* __restrict__ Wt,
                      const float* __restrict__ bias,
                      half_t* __restrict__ Qh, half_t* __restrict__ Kh,
                      half_t* __restrict__ Vf) {
  __shared__ half_t sA[128 * 32];
  __shared__ half_t sB[128 * 32];
  const int t = threadIdx.x;
  const int m0 = blockIdx.y * 128;
  const int n0 = blockIdx.x * 128;
  const int lane = t & 63, wid = t >> 6;
  const int wr = (wid >> 1) * 64, wc = (wid & 1) * 64;
  const int lrow = lane & 15, lks = lane >> 4;
  const int s1 = t, s2 = t + 256;
  const int ar1 = s1 >> 2, ac1 = (s1 & 3) * 8;
  const int ar2 = s2 >> 2, ac2 = (s2 & 3) * 8;

  f32x4 acc[4][4] = {};

  for (int k0 = 0; k0 < HID; k0 += 32) {
    __syncthreads();
    GLOAD_LDS16(xh + (size_t)(m0 + ar1) * HID + k0 + ac1, &sA[s1 * 8]);
    GLOAD_LDS16(xh + (size_t)(m0 + ar2) * HID + k0 + ac2, &sA[s2 * 8]);
    GLOAD_LDS16(Wt + (size_t)(n0 + ar1) * HID + k0 + ac1, &sB[s1 * 8]);
    GLOAD_LDS16(Wt + (size_t)(n0 + ar2) * HID + k0 + ac2, &sB[s2 * 8]);
    __syncthreads();
    half8 a[4], b[4];
#pragma unroll
    for (int m = 0; m < 4; ++m)
      a[m] = *reinterpret_cast<const half8*>(&sA[(wr + m * 16 + lrow) * 32 + lks * 8]);
#pragma unroll
    for (int n = 0; n < 4; ++n)
      b[n] = *reinterpret_cast<const half8*>(&sB[(wc + n * 16 + lrow) * 32 + lks * 8]);
#pragma unroll
    for (int m = 0; m < 4; ++m)
#pragma unroll
      for (int n = 0; n < 4; ++n)
        acc[m][n] = __builtin_amdgcn_mfma_f32_16x16x32_f16(a[m], b[n], acc[m][n], 0, 0, 0);
  }

  const float scale = 0.04419417382415922f;  // 1/sqrt(512)
  const int region = n0 >> 9;  // 0=Q, 1=K, 2=V (uniform per block)
#pragma unroll
  for (int m = 0; m < 4; ++m) {
#pragma unroll
    for (int n = 0; n < 4; ++n) {
      const int col = n0 + wc + n * 16 + lrow;
#pragma unroll
      for (int r = 0; r < 4; ++r) {
        const int row = m0 + wr + m * 16 + lks * 4 + r;
        float v = acc[m][n][r] + bias[col];
        if (region == 0) {
          Qh[(size_t)row * HID + col] = (half_t)(v * scale);
        } else if (region == 1) {
          Kh[(size_t)row * HID + (col - 512)] = (half_t)v;
        } else {
          const int bb = row >> 12, s = row & (SEQ - 1), h = col - 1024;
          const int tl = bb * 4096 + (s >> 5) * 32 + (h >> 4);
          Vf[(size_t)tl * 512 + (((h & 15) | (((s >> 3) & 3) << 4)) * 8) + (s & 7)] =
              (half_t)v;
        }
      }
    }
  }
}

// ---------------- scores = Q @ K^T -> f16 raw scores + softmax partials ----------
template <int FRAG>
__launch_bounds__(256)
__global__ void k_qk(const half_t* __restrict__ Qh, const half_t* __restrict__ Kh,
                     half_t* __restrict__ Sh, float2* __restrict__ part) {
  __shared__ half_t sA[128 * 32];
  __shared__ half_t sB[128 * 32];
  __shared__ float lm[2][128], ls[2][128];
  const int t = threadIdx.x;
  const int bz = blockIdx.z;
  const half_t* A = Qh + (size_t)bz * SEQ * HID;
  const half_t* B = Kh + (size_t)bz * SEQ * HID;
  const int m0 = blockIdx.y * 128;
  const int n0 = blockIdx.x * 128;
  const int lane = t & 63, wid = t >> 6;
  const int wr = (wid >> 1) * 64, wc = (wid & 1) * 64;
  const int lrow = lane & 15, lks = lane >> 4;
  const int s1 = t, s2 = t + 256;
  const int ar1 = s1 >> 2, ac1 = (s1 & 3) * 8;
  const int ar2 = s2 >> 2, ac2 = (s2 & 3) * 8;

  f32x4 acc[4][4] = {};

  for (int k0 = 0; k0 < HID; k0 += 32) {
    __syncthreads();
    GLOAD_LDS16(A + (size_t)(m0 + ar1) * HID + k0 + ac1, &sA[s1 * 8]);
    GLOAD_LDS16(A + (size_t)(m0 + ar2) * HID + k0 + ac2, &sA[s2 * 8]);
    GLOAD_LDS16(B + (size_t)(n0 + ar1) * HID + k0 + ac1, &sB[s1 * 8]);
    GLOAD_LDS16(B + (size_t)(n0 + ar2) * HID + k0 + ac2, &sB[s2 * 8]);
    __syncthreads();
    half8 a[4], b[4];
#pragma unroll
    for (int m = 0; m < 4; ++m)
      a[m] = *reinterpret_cast<const half8*>(&sA[(wr + m * 16 + lrow) * 32 + lks * 8]);
#pragma unroll
    for (int n = 0; n < 4; ++n)
      b[n] = *reinterpret_cast<const half8*>(&sB[(wc + n * 16 + lrow) * 32 + lks * 8]);
#pragma unroll
    for (int m = 0; m < 4; ++m)
#pragma unroll
      for (int n = 0; n < 4; ++n)
        acc[m][n] = __builtin_amdgcn_mfma_f32_16x16x32_f16(a[m], b[n], acc[m][n], 0, 0, 0);
  }

  // f16 raw-score write
#pragma unroll
  for (int m = 0; m < 4; ++m)
#pragma unroll
    for (int n = 0; n < 4; ++n)
#pragma unroll
      for (int r = 0; r < 4; ++r) {
        const int row = m0 + wr + m * 16 + lks * 4 + r;
        const int key = n0 + wc + n * 16 + lrow;
        if (FRAG) {
          Sh[((size_t)(bz * 128 + (key >> 5)) * 256 + (row >> 4)) * 512 +
             (((row & 15) | (((key >> 3) & 3) << 4)) * 8) + (key & 7)] =
              (half_t)acc[m][n][r];
        } else {
          Sh[((size_t)bz * SEQ + row) * (2 * SEQ) + SEQ + key] = (half_t)acc[m][n][r];
        }
      }

  // per-tile softmax partials
#pragma unroll
  for (int m = 0; m < 4; ++m) {
#pragma unroll
    for (int r = 0; r < 4; ++r) {
      float mx = fmaxf(fmaxf(acc[m][0][r], acc[m][1][r]),
                       fmaxf(acc[m][2][r], acc[m][3][r]));
      mx = fmaxf(mx, __shfl_xor(mx, 1));
      mx = fmaxf(mx, __shfl_xor(mx, 2));
      mx = fmaxf(mx, __shfl_xor(mx, 4));
      mx = fmaxf(mx, __shfl_xor(mx, 8));
      float s = expf(acc[m][0][r] - mx) + expf(acc[m][1][r] - mx) +
                expf(acc[m][2][r] - mx) + expf(acc[m][3][r] - mx);
      s += __shfl_xor(s, 1);
      s += __shfl_xor(s, 2);
      s += __shfl_xor(s, 4);
      s += __shfl_xor(s, 8);
      if (lrow == 0) {
        const int rr = wr + m * 16 + lks * 4 + r;
        lm[wid & 1][rr] = mx;
        ls[wid & 1][rr] = s;
      }
    }
  }
  __syncthreads();
  if (t < 128) {
    const float m0v = lm[0][t], m1v = lm[1][t];
    const float M = fmaxf(m0v, m1v);
    const float L = ls[0][t] * expf(m0v - M) + ls[1][t] * expf(m1v - M);
    part[(size_t)(bz * SEQ + m0 + t) * 32 + blockIdx.x] = make_float2(M, L);
  }
}

// ---------------- merge 32 per-tile partials per row -> (rowmax, 1/rowsum) --------
__global__ void k_lred(const float2* __restrict__ part, float2* __restrict__ stats) {
  const int row = blockIdx.x * 256 + threadIdx.x;  // [0, NB*SEQ)
  const float2* p = part + (size_t)row * 32;
  float M = -3.4028235e38f;
#pragma unroll
  for (int i = 0; i < 32; ++i) M = fmaxf(M, p[i].x);
  float L = 0.f;
#pragma unroll
  for (int i = 0; i < 32; ++i) L += p[i].y * expf(p[i].x - M);
  stats[row] = make_float2(M, 1.0f / L);
}

// ---------------- BARRIER-FREE fused PV: R13 occupancy x R14 row-private exp ------
// 256 blocks x 8 waves (512 thr, 2 blocks/CU = 16 waves/CU). Wave grid 4x2:
// wave (wr,wc) owns 16 PRIVATE rows x 256 cols. Exp duplication 2x (col halves).
// A-frag = 1KB contiguous per kc (depth-2 reg prefetch, L3-resident Shf).
// wc=0 wave stores the f32 attn chunk (32B/lane contiguous; 4 lks lanes complete
// each 128B row-line). il folded into exponent. No LDS, no barriers.
__launch_bounds__(512, 4)
__global__ void k_pvh(const half_t* __restrict__ Shf, const half_t* __restrict__ Vf,
                      const float2* __restrict__ stats,
                      float* __restrict__ attn, float* __restrict__ O) {
  const int t = threadIdx.x;
  const int bid = blockIdx.x;
  const int sw = (bid & 7) * 32 + (bid >> 3);  // bijective XCD swizzle (256)
  const int bz = sw >> 6;
  const int m0 = (sw & 63) * 64;
  const int lane = t & 63, wid = t >> 6;
  const int wr = wid & 3, wc = wid >> 2;
  const int lrow = lane & 15, lks = lane >> 4;

  const int rg = (m0 >> 4) + wr;               // wave's row-group within batch
  const int rowA = m0 + wr * 16 + lrow;        // lane's row
  const float2 st = stats[(size_t)bz * SEQ + rowA];
  const float m2p = st.x * LOG2E - __log2f(st.y);

  const half_t* const abase =
      Shf + ((size_t)(bz * 128) * 256 + rg) * 512 + lane * 8;
  const half_t* const vb =
      Vf + ((size_t)bz * 4096 + wc * 16) * 512 + lane * 8;
  float* const arow =
      attn + (size_t)bz * SEQ * SEQ + (size_t)rowA * SEQ + lks * 8;
  float* const Ob = O + (size_t)bz * SEQ * HID;

  f32x4 acc[16] = {};
  half8 arA, arB;
  arA = *reinterpret_cast<const half8*>(abase);
  arB = *reinterpret_cast<const half8*>(abase + (size_t)256 * 512);

#define PVH_STEP(AR, KC)                                                     \
  {                                                                          \
    f32x4 e0, e1;                                                            \
    half8 ah;                                                                \
    _Pragma("unroll")                                                        \
    for (int j = 0; j < 4; ++j) {                                            \
      e0[j] = exp2f((float)(AR)[j] * LOG2E - m2p);                           \
      e1[j] = exp2f((float)(AR)[j + 4] * LOG2E - m2p);                       \
    }                                                                        \
    _Pragma("unroll")                                                        \
    for (int j = 0; j < 4; ++j) {                                            \
      ah[j] = (half_t)e0[j];                                                 \
      ah[j + 4] = (half_t)e1[j];                                             \
    }                                                                        \
    if ((KC) + 2 < 128)                                                      \
      AR = *reinterpret_cast<const half8*>(abase +                           \
                                           (size_t)((KC) + 2) * 256 * 512);  \
    if (wc == 0) {                                                           \
      *reinterpret_cast<f32x4*>(arow + (KC) * 32) = e0;                      \
      *reinterpret_cast<f32x4*>(arow + (KC) * 32 + 4) = e1;                  \
    }                                                                        \
    _Pragma("unroll")                                                        \
    for (int g = 0; g < 4; ++g) {                                            \
      half8 bv[4];                                                           \
      _Pragma("unroll")                                                      \
      for (int n = 0; n < 4; ++n)                                            \
        bv[n] = *reinterpret_cast<const half8*>(                             \
            vb + ((size_t)(KC) * 32 + g * 4 + n) * 512);                     \
      _Pragma("unroll")                                                      \
      for (int n = 0; n < 4; ++n)                                            \
        acc[g * 4 + n] = __builtin_amdgcn_mfma_f32_16x16x32_f16(             \
            ah, bv[n], acc[g * 4 + n], 0, 0, 0);                             \
    }                                                                        \
  }

  for (int kc = 0; kc < 128; kc += 2) {
    PVH_STEP(arA, kc);
    PVH_STEP(arB, kc + 1);
  }

#pragma unroll
  for (int n = 0; n < 16; ++n)
#pragma unroll
    for (int r = 0; r < 4; ++r)
      Ob[(size_t)(m0 + wr * 16 + lks * 4 + r) * HID + wc * 256 + n * 16 + lrow] =
          acc[n][r];
}

// ---------------- fallback PV (R9 known-good) ----------------
__launch_bounds__(512, 4)
__global__ void k_pvn(float* __restrict__ P, const half_t* __restrict__ Vf,
                      const float2* __restrict__ stats, float* __restrict__ O) {
  __shared__ half_t sA[4][32 * 64];
  const int t = threadIdx.x;
  const int bid = blockIdx.x;
  const int sw = (bid & 7) * 64 + (bid >> 3);
  const int bz = sw >> 7;
  const int m0 = (sw & 127) * 32;

  float* Pb = P + (size_t)bz * SEQ * SEQ;
  float* Ob = O + (size_t)bz * SEQ * HID;

  const int lane = t & 63, wid = t >> 6;
  const int lrow = lane & 15, lks = lane >> 4;

  const int prow = t >> 4;
  const int pc = t & 15;
  const float2 st = stats[(size_t)bz * SEQ + m0 + prow];
  const float mrow2 = st.x * LOG2E, invl = st.y;

  float* const PArow = Pb + (size_t)(m0 + prow) * SEQ + pc * 8;
  const half_t* const Shrow =
      (const half_t*)(Pb + (size_t)(m0 + prow) * SEQ) + SEQ + pc * 8;

  const int schunk = pc >> 3;
  const int sidx = prow * 64 + (((pc & 7) ^ (prow & 7)) << 3);

  int aoff[2][2];
#pragma unroll
  for (int m = 0; m < 2; ++m)
#pragma unroll
    for (int kk = 0; kk < 2; ++kk) {
      const int row = m * 16 + lrow;
      aoff[m][kk] = row * 64 + (((kk * 4 + lks) ^ (row & 7)) << 3);
    }

  const half_t* const vb =
      Vf + (size_t)bz * 4096 * 512 + (size_t)(wid * 4) * 512 + lane * 8;

  f32x4 acc[2][4] = {};
  f32x4 e0, e1;
  half8 prA, prB;

#define PV_EXPSTAGE(SB, PR)                                                  \
  {                                                                          \
    _Pragma("unroll")                                                        \
    for (int j = 0; j < 4; ++j) {                                            \
      e0[j] = exp2f((float)(PR)[j] * LOG2E - mrow2) * invl;                  \
      e1[j] = exp2f((float)(PR)[j + 4] * LOG2E - mrow2) * invl;              \
    }                                                                        \
    half8 hv;                                                                \
    _Pragma("unroll")                                                        \
    for (int j = 0; j < 4; ++j) {                                            \
      hv[j] = (half_t)e0[j];                                                 \
      hv[j + 4] = (half_t)e1[j];                                             \
    }                                                                        \
    *reinterpret_cast<half8*>(&sA[(SB) * 2 + schunk][sidx]) = hv;            \
  }

#define PV_ITER(PRL, PRC, SC)                                                \
  {                                                                          \
    half8 b[16];                                                             \
    _Pragma("unroll")                                                        \
    for (int kc = 0; kc < 4; ++kc)                                           \
      _Pragma("unroll")                                                      \
      for (int n = 0; n < 4; ++n)                                            \
        b[kc * 4 + n] = *reinterpret_cast<const half8*>(                     \
            vb + ((size_t)((SC) * 4 + kc) * 32 + n) * 512);                  \
    if ((SC) + 2 < 32)                                                       \
      PRL = *reinterpret_cast<const half8*>(Shrow + ((SC) + 2) * 128);       \
    *reinterpret_cast<f32x4*>(PArow + (SC) * 128) = e0;                      \
    *reinterpret_cast<f32x4*>(PArow + (SC) * 128 + 4) = e1;                  \
    __builtin_amdgcn_sched_barrier(0);                                       \
    _Pragma("unroll")                                                        \
    for (int kc = 0; kc < 4; ++kc) {                                         \
      const int cb = ((SC) & 1) * 2 + (kc >> 1);                             \
      half8 a[2];                                                            \
      _Pragma("unroll")                                                      \
      for (int m = 0; m < 2; ++m)                                            \
        a[m] = *reinterpret_cast<const half8*>(&sA[cb][aoff[m][kc & 1]]);    \
      _Pragma("unroll")                                                      \
      for (int m = 0; m < 2; ++m)                                            \
        _Pragma("unroll")                                                    \
        for (int n = 0; n < 4; ++n)                                          \
          acc[m][n] = __builtin_amdgcn_mfma_f32_16x16x32_f16(                \
              a[m], b[kc * 4 + n], acc[m][n], 0, 0, 0);                      \
    }                                                                        \
    if ((SC) + 1 < 32) {                                                     \
      PV_EXPSTAGE(((SC) + 1) & 1, PRC);                                      \
    }                                                                        \
    LGKM_BARRIER();                                                          \
  }

  {
    half8 pr0 = *reinterpret_cast<const half8*>(Shrow);
    PV_EXPSTAGE(0, pr0);
    prB = *reinterpret_cast<const half8*>(Shrow + 128);
    LGKM_BARRIER();
  }

  for (int sc = 0; sc < 32; sc += 2) {
    PV_ITER(prA, prB, sc);
    PV_ITER(prB, prA, sc + 1);
  }

#pragma unroll
  for (int m = 0; m < 2; ++m)
#pragma unroll
    for (int n = 0; n < 4; ++n)
#pragma unroll
      for (int r = 0; r < 4; ++r)
        Ob[(size_t)(m0 + m * 16 + lks * 4 + r) * HID + (wid * 64 + n * 16 + lrow)] =
            acc[m][n][r];
}

extern "C" void kernel_launch(void* const* d_in, const int* in_sizes, int n_in,
                              void* d_out, int out_size, void* d_ws, size_t ws_size,
                              hipStream_t stream) {
  const float* x = (const float*)d_in[0];     // [4,4096,512]
  const float* W = (const float*)d_in[1];     // [512,1536]
  const float* bias = (const float*)d_in[2];  // [1536]
  float* opt = (float*)d_out;                        // [4*4096*512]
  float* attn = opt + (size_t)NB * SEQ * HID;        // [4*4096*4096]

  half_t* xh = (half_t*)d_ws;                        // 16.78 MB
  half_t* Wt = xh + (size_t)NB * SEQ * HID;          // 1.57 MB
  half_t* Qh = Wt + (size_t)N3 * HID;                // 16.78 MB
  half_t* Kh = Qh + (size_t)NB * SEQ * HID;          // 16.78 MB
  half_t* Vf = Kh + (size_t)NB * SEQ * HID;          // 16.78 MB (fragment-packed)
  float2* part = (float2*)(Vf + (size_t)NB * HID * SEQ);  // 4.19 MB
  float2* stats = part + (size_t)NB * SEQ * 32;           // 131 KB
  half_t* Shf = (half_t*)(stats + NB * SEQ);              // 134.2 MB (frag scores)
  const size_t need = (size_t)((char*)(Shf + (size_t)NB * SEQ * SEQ) - (char*)d_ws);
  const bool frag = ws_size >= need;

  k_cvt<<<2048, 256, 0, stream>>>(x, xh, NB * SEQ * HID / 4);
  k_tw<<<dim3(N3 / 64, HID / 64), 256, 0, stream>>>(W, Wt);
  k_qkv<<<dim3(N3 / 128, NB * SEQ / 128), 256, 0, stream>>>(xh, Wt, bias, Qh, Kh, Vf);
  if (frag) {
    k_qk<1><<<dim3(SEQ / 128, SEQ / 128, NB), 256, 0, stream>>>(Qh, Kh, Shf, part);
    k_lred<<<NB * SEQ / 256, 256, 0, stream>>>(part, stats);
    k_pvh<<<256, 512, 0, stream>>>(Shf, Vf, stats, attn, opt);
  } else {
    k_qk<0><<<dim3(SEQ / 128, SEQ / 128, NB), 256, 0, stream>>>(Qh, Kh, (half_t*)attn,
                                                                part);
    k_lred<<<NB * SEQ / 256, 256, 0, stream>>>(part, stats);
    k_pvn<<<512, 512, 0, stream>>>(attn, Vf, stats, opt);
  }
}

// Round 16
// 451.434 us; speedup vs baseline: 1.5222x; 1.3366x over previous
//
#include <hip/hip_runtime.h>

#define SEQ 4096
#define HID 512
#define NB  4
#define N3  1536
#define LOG2E 1.4426950408889634f

typedef _Float16 half_t;
typedef __attribute__((ext_vector_type(8))) _Float16 half8;
typedef __attribute__((ext_vector_type(4))) float f32x4;

#define GLOAD_LDS16(gp, lp) __builtin_amdgcn_global_load_lds((gp), (lp), 16, 0, 0)

// ---------------- convert x (f32) -> f16 ----------------
__global__ void k_cvt(const float* __restrict__ x, half_t* __restrict__ xh, int n4) {
  int i = blockIdx.x * blockDim.x + threadIdx.x;
  int stride = gridDim.x * blockDim.x;
  for (; i < n4; i += stride) {
    float4 v = reinterpret_cast<const float4*>(x)[i];
    union { half_t h[4]; short4 s; } u;
    u.h[0] = (half_t)v.x; u.h[1] = (half_t)v.y;
    u.h[2] = (half_t)v.z; u.h[3] = (half_t)v.w;
    reinterpret_cast<short4*>(xh)[i] = u.s;
  }
}

// ---------------- W [512][1536] f32 -> Wt [1536][512] f16 ----------------
__global__ void k_tw(const float* __restrict__ W, half_t* __restrict__ Wt) {
  __shared__ half_t tile[64][65];
  const int n0 = blockIdx.x * 64;
  const int k0 = blockIdx.y * 64;
  const int tx = threadIdx.x & 63, ty = threadIdx.x >> 6;
#pragma unroll
  for (int i = 0; i < 64; i += 4)
    tile[ty + i][tx] = (half_t)W[(size_t)(k0 + ty + i) * N3 + n0 + tx];
  __syncthreads();
#pragma unroll
  for (int i = 0; i < 64; i += 4)
    Wt[(size_t)(n0 + ty + i) * HID + k0 + tx] = tile[tx][ty + i];
}

// ---------------- QKV projection GEMM (V written transposed [b][h][s]) ----------
__launch_bounds__(256)
__global__ void k_qkv(const half_t* __restrict__ xh, const half_t* __restrict__ Wt,
                      const float* __restrict__ bias,
                      half_t* __restrict__ Qh, half_t* __restrict__ Kh,
                      half_t* __restrict__ Vt) {
  __shared__ half_t sA[128 * 32];
  __shared__ half_t sB[128 * 32];
  const int t = threadIdx.x;
  const int m0 = blockIdx.y * 128;
  const int n0 = blockIdx.x * 128;
  const int lane = t & 63, wid = t >> 6;
  const int wr = (wid >> 1) * 64, wc = (wid & 1) * 64;
  const int lrow = lane & 15, lks = lane >> 4;
  const int s1 = t, s2 = t + 256;
  const int ar1 = s1 >> 2, ac1 = (s1 & 3) * 8;
  const int ar2 = s2 >> 2, ac2 = (s2 & 3) * 8;

  f32x4 acc[4][4] = {};

  for (int k0 = 0; k0 < HID; k0 += 32) {
    __syncthreads();
    GLOAD_LDS16(xh + (size_t)(m0 + ar1) * HID + k0 + ac1, &sA[s1 * 8]);
    GLOAD_LDS16(xh + (size_t)(m0 + ar2) * HID + k0 + ac2, &sA[s2 * 8]);
    GLOAD_LDS16(Wt + (size_t)(n0 + ar1) * HID + k0 + ac1, &sB[s1 * 8]);
    GLOAD_LDS16(Wt + (size_t)(n0 + ar2) * HID + k0 + ac2, &sB[s2 * 8]);
    __syncthreads();
    half8 a[4], b[4];
#pragma unroll
    for (int m = 0; m < 4; ++m)
      a[m] = *reinterpret_cast<const half8*>(&sA[(wr + m * 16 + lrow) * 32 + lks * 8]);
#pragma unroll
    for (int n = 0; n < 4; ++n)
      b[n] = *reinterpret_cast<const half8*>(&sB[(wc + n * 16 + lrow) * 32 + lks * 8]);
#pragma unroll
    for (int m = 0; m < 4; ++m)
#pragma unroll
      for (int n = 0; n < 4; ++n)
        acc[m][n] = __builtin_amdgcn_mfma_f32_16x16x32_f16(a[m], b[n], acc[m][n], 0, 0, 0);
  }

  const float scale = 0.04419417382415922f;  // 1/sqrt(512)
  const int region = n0 >> 9;  // 0=Q, 1=K, 2=V (uniform per block)
#pragma unroll
  for (int m = 0; m < 4; ++m) {
#pragma unroll
    for (int n = 0; n < 4; ++n) {
      const int col = n0 + wc + n * 16 + lrow;
#pragma unroll
      for (int r = 0; r < 4; ++r) {
        const int row = m0 + wr + m * 16 + lks * 4 + r;
        float v = acc[m][n][r] + bias[col];
        if (region == 0) {
          Qh[(size_t)row * HID + col] = (half_t)(v * scale);
        } else if (region == 1) {
          Kh[(size_t)row * HID + (col - 512)] = (half_t)v;
        } else {
          const int bb = row >> 12, ml = row & (SEQ - 1);
          Vt[((size_t)bb * HID + (col - 1024)) * SEQ + ml] = (half_t)v;
        }
      }
    }
  }
}

// ---------------- scores = Q @ K^T -> f16 Sh (packed in attn rows) + partials ----
__launch_bounds__(256)
__global__ void k_qk(const half_t* __restrict__ Qh, const half_t* __restrict__ Kh,
                     float* __restrict__ S, float2* __restrict__ part) {
  __shared__ half_t sA[128 * 32];
  __shared__ half_t sB[128 * 32];
  __shared__ float lm[2][128], ls[2][128];
  const int t = threadIdx.x;
  const int bz = blockIdx.z;
  const half_t* A = Qh + (size_t)bz * SEQ * HID;
  const half_t* B = Kh + (size_t)bz * SEQ * HID;
  half_t* Ch = (half_t*)(S + (size_t)bz * SEQ * SEQ);
  const int m0 = blockIdx.y * 128;
  const int n0 = blockIdx.x * 128;
  const int lane = t & 63, wid = t >> 6;
  const int wr = (wid >> 1) * 64, wc = (wid & 1) * 64;
  const int lrow = lane & 15, lks = lane >> 4;
  const int s1 = t, s2 = t + 256;
  const int ar1 = s1 >> 2, ac1 = (s1 & 3) * 8;
  const int ar2 = s2 >> 2, ac2 = (s2 & 3) * 8;

  f32x4 acc[4][4] = {};

  for (int k0 = 0; k0 < HID; k0 += 32) {
    __syncthreads();
    GLOAD_LDS16(A + (size_t)(m0 + ar1) * HID + k0 + ac1, &sA[s1 * 8]);
    GLOAD_LDS16(A + (size_t)(m0 + ar2) * HID + k0 + ac2, &sA[s2 * 8]);
    GLOAD_LDS16(B + (size_t)(n0 + ar1) * HID + k0 + ac1, &sB[s1 * 8]);
    GLOAD_LDS16(B + (size_t)(n0 + ar2) * HID + k0 + ac2, &sB[s2 * 8]);
    __syncthreads();
    half8 a[4], b[4];
#pragma unroll
    for (int m = 0; m < 4; ++m)
      a[m] = *reinterpret_cast<const half8*>(&sA[(wr + m * 16 + lrow) * 32 + lks * 8]);
#pragma unroll
    for (int n = 0; n < 4; ++n)
      b[n] = *reinterpret_cast<const half8*>(&sB[(wc + n * 16 + lrow) * 32 + lks * 8]);
#pragma unroll
    for (int m = 0; m < 4; ++m)
#pragma unroll
      for (int n = 0; n < 4; ++n)
        acc[m][n] = __builtin_amdgcn_mfma_f32_16x16x32_f16(a[m], b[n], acc[m][n], 0, 0, 0);
  }

  // f16 raw-score write into the packed Sh slots (row bytes [8192,16384))
#pragma unroll
  for (int m = 0; m < 4; ++m)
#pragma unroll
    for (int n = 0; n < 4; ++n)
#pragma unroll
      for (int r = 0; r < 4; ++r)
        Ch[(size_t)(m0 + wr + m * 16 + lks * 4 + r) * (2 * SEQ) + SEQ +
           (n0 + wc + n * 16 + lrow)] = (half_t)acc[m][n][r];

  // per-tile softmax partials
#pragma unroll
  for (int m = 0; m < 4; ++m) {
#pragma unroll
    for (int r = 0; r < 4; ++r) {
      float mx = fmaxf(fmaxf(acc[m][0][r], acc[m][1][r]),
                       fmaxf(acc[m][2][r], acc[m][3][r]));
      mx = fmaxf(mx, __shfl_xor(mx, 1));
      mx = fmaxf(mx, __shfl_xor(mx, 2));
      mx = fmaxf(mx, __shfl_xor(mx, 4));
      mx = fmaxf(mx, __shfl_xor(mx, 8));
      float s = expf(acc[m][0][r] - mx) + expf(acc[m][1][r] - mx) +
                expf(acc[m][2][r] - mx) + expf(acc[m][3][r] - mx);
      s += __shfl_xor(s, 1);
      s += __shfl_xor(s, 2);
      s += __shfl_xor(s, 4);
      s += __shfl_xor(s, 8);
      if (lrow == 0) {
        const int rr = wr + m * 16 + lks * 4 + r;
        lm[wid & 1][rr] = mx;
        ls[wid & 1][rr] = s;
      }
    }
  }
  __syncthreads();
  if (t < 128) {
    const float m0v = lm[0][t], m1v = lm[1][t];
    const float M = fmaxf(m0v, m1v);
    const float L = ls[0][t] * expf(m0v - M) + ls[1][t] * expf(m1v - M);
    part[(size_t)(bz * SEQ + m0 + t) * 32 + blockIdx.x] = make_float2(M, L);
  }
}

// ---------------- merge 32 per-tile partials per row -> (rowmax, 1/rowsum) --------
__global__ void k_lred(const float2* __restrict__ part, float2* __restrict__ stats) {
  const int row = blockIdx.x * 256 + threadIdx.x;  // [0, NB*SEQ)
  const float2* p = part + (size_t)row * 32;
  float M = -3.4028235e38f;
#pragma unroll
  for (int i = 0; i < 32; ++i) M = fmaxf(M, p[i].x);
  float L = 0.f;
#pragma unroll
  for (int i = 0; i < 32; ++i) L += p[i].y * expf(p[i].x - M);
  stats[row] = make_float2(M, 1.0f / L);
}

// ---------------- streaming softmax: Sh(f16) -> f32 attn row + f16 Ph row --------
// One wave per row. Load the row's entire 8KB Sh into registers, fence vmcnt(0)
// (all reads retired BEFORE any store -> in-row overwrite is safe), exp with
// invl folded into the exponent, write 16KB f32 attn + 8KB f16 Ph. Pure BW.
__launch_bounds__(256)
__global__ void k_sm(float* __restrict__ attn, const float2* __restrict__ stats,
                     half_t* __restrict__ Ph) {
  const int row = blockIdx.x * 4 + (threadIdx.x >> 6);  // [0, NB*SEQ)
  const int lane = threadIdx.x & 63;
  const int bz = row >> 12, r = row & (SEQ - 1);
  float* const arow = attn + (size_t)bz * SEQ * SEQ + (size_t)r * SEQ;
  const half_t* const sh = (const half_t*)arow + SEQ + lane * 8;
  half_t* const ph = Ph + (size_t)row * SEQ + lane * 8;
  const float2 st = stats[row];
  const float m2p = st.x * LOG2E - __log2f(st.y);  // exp(s-M)*invl = 2^(s*l2e - m2p)

  half8 s[8];
#pragma unroll
  for (int j = 0; j < 8; ++j)
    s[j] = *reinterpret_cast<const half8*>(sh + j * 512);
  asm volatile("s_waitcnt vmcnt(0)" ::: "memory");
  __builtin_amdgcn_sched_barrier(0);

#pragma unroll
  for (int j = 0; j < 8; ++j) {
    f32x4 e0, e1;
    half8 hv;
#pragma unroll
    for (int q = 0; q < 4; ++q) {
      e0[q] = exp2f((float)s[j][q] * LOG2E - m2p);
      e1[q] = exp2f((float)s[j][q + 4] * LOG2E - m2p);
    }
#pragma unroll
    for (int q = 0; q < 4; ++q) {
      hv[q] = (half_t)e0[q];
      hv[q + 4] = (half_t)e1[q];
    }
    *reinterpret_cast<f32x4*>(arow + j * 512 + lane * 8) = e0;
    *reinterpret_cast<f32x4*>(arow + j * 512 + lane * 8 + 4) = e1;
    *reinterpret_cast<half8*>(ph + j * 512) = hv;
  }
}

// ---------------- pure GEMM: opt = Ph @ Vt^T (m97 structure, K=4096) ------------
__launch_bounds__(256)
__global__ void k_pv(const half_t* __restrict__ Ph, const half_t* __restrict__ Vt,
                     float* __restrict__ O) {
  __shared__ half_t sA[128 * 32];
  __shared__ half_t sB[128 * 32];
  const int t = threadIdx.x;
  const int bz = blockIdx.z;
  const half_t* A = Ph + (size_t)bz * SEQ * SEQ;   // [4096][4096]
  const half_t* B = Vt + (size_t)bz * HID * SEQ;   // [512][4096]
  float* C = O + (size_t)bz * SEQ * HID;
  const int m0 = blockIdx.y * 128;
  const int n0 = blockIdx.x * 128;
  const int lane = t & 63, wid = t >> 6;
  const int wr = (wid >> 1) * 64, wc = (wid & 1) * 64;
  const int lrow = lane & 15, lks = lane >> 4;
  const int s1 = t, s2 = t + 256;
  const int ar1 = s1 >> 2, ac1 = (s1 & 3) * 8;
  const int ar2 = s2 >> 2, ac2 = (s2 & 3) * 8;

  f32x4 acc[4][4] = {};

  for (int k0 = 0; k0 < SEQ; k0 += 32) {
    __syncthreads();
    GLOAD_LDS16(A + (size_t)(m0 + ar1) * SEQ + k0 + ac1, &sA[s1 * 8]);
    GLOAD_LDS16(A + (size_t)(m0 + ar2) * SEQ + k0 + ac2, &sA[s2 * 8]);
    GLOAD_LDS16(B + (size_t)(n0 + ar1) * SEQ + k0 + ac1, &sB[s1 * 8]);
    GLOAD_LDS16(B + (size_t)(n0 + ar2) * SEQ + k0 + ac2, &sB[s2 * 8]);
    __syncthreads();
    half8 a[4], b[4];
#pragma unroll
    for (int m = 0; m < 4; ++m)
      a[m] = *reinterpret_cast<const half8*>(&sA[(wr + m * 16 + lrow) * 32 + lks * 8]);
#pragma unroll
    for (int n = 0; n < 4; ++n)
      b[n] = *reinterpret_cast<const half8*>(&sB[(wc + n * 16 + lrow) * 32 + lks * 8]);
#pragma unroll
    for (int m = 0; m < 4; ++m)
#pragma unroll
      for (int n = 0; n < 4; ++n)
        acc[m][n] = __builtin_amdgcn_mfma_f32_16x16x32_f16(a[m], b[n], acc[m][n], 0, 0, 0);
  }

#pragma unroll
  for (int m = 0; m < 4; ++m)
#pragma unroll
    for (int n = 0; n < 4; ++n)
#pragma unroll
      for (int r = 0; r < 4; ++r)
        C[(size_t)(m0 + wr + m * 16 + lks * 4 + r) * HID + (n0 + wc + n * 16 + lrow)] =
            acc[m][n][r];
}

extern "C" void kernel_launch(void* const* d_in, const int* in_sizes, int n_in,
                              void* d_out, int out_size, void* d_ws, size_t ws_size,
                              hipStream_t stream) {
  const float* x = (const float*)d_in[0];     // [4,4096,512]
  const float* W = (const float*)d_in[1];     // [512,1536]
  const float* bias = (const float*)d_in[2];  // [1536]
  float* opt = (float*)d_out;                        // [4*4096*512]
  float* attn = opt + (size_t)NB * SEQ * HID;        // [4*4096*4096]

  half_t* xh = (half_t*)d_ws;                        // 16.78 MB
  half_t* Wt = xh + (size_t)NB * SEQ * HID;          // 1.57 MB
  half_t* Qh = Wt + (size_t)N3 * HID;                // 16.78 MB
  half_t* Kh = Qh + (size_t)NB * SEQ * HID;          // 16.78 MB
  half_t* Vt = Kh + (size_t)NB * SEQ * HID;          // 16.78 MB ([b][h][s])
  float2* part = (float2*)(Vt + (size_t)NB * HID * SEQ);  // 4.19 MB
  float2* stats = part + (size_t)NB * SEQ * 32;           // 131 KB
  half_t* Ph = (half_t*)(stats + NB * SEQ);               // 134.2 MB (exp'd f16 P)

  k_cvt<<<2048, 256, 0, stream>>>(x, xh, NB * SEQ * HID / 4);
  k_tw<<<dim3(N3 / 64, HID / 64), 256, 0, stream>>>(W, Wt);
  k_qkv<<<dim3(N3 / 128, NB * SEQ / 128), 256, 0, stream>>>(xh, Wt, bias, Qh, Kh, Vt);
  k_qk<<<dim3(SEQ / 128, SEQ / 128, NB), 256, 0, stream>>>(Qh, Kh, attn, part);
  k_lred<<<NB * SEQ / 256, 256, 0, stream>>>(part, stats);
  k_sm<<<NB * SEQ / 4, 256, 0, stream>>>(attn, stats, Ph);
  k_pv<<<dim3(HID / 128, SEQ / 128, NB), 256, 0, stream>>>(Ph, Vt, opt);
}